// Round 4
// baseline (82956.653 us; speedup 1.0000x reference)
//
#include <hip/hip_runtime.h>
#include <math.h>

#define KBEAM 10
#define TSTEPS 70
#define EOS_TOK 2
#define PAD_TOK 0
#define START_TOK 1
#define EDIM 1024
#define HDIM 1024
#define VOCAB 32000
#define SLEN 128
#define NEGF (-1000000000.0f)
#define TOKW (TSTEPS + 1)   // 71
#define NBLK 512            // persistent grid: 2 blocks/CU on 256 CUs, co-resident by construction

__device__ inline float wsum(float v) {
#pragma unroll
  for (int m = 32; m; m >>= 1) v += __shfl_xor(v, m, 64);
  return v;
}
__device__ inline float sigmoidf(float x) { return 1.0f / (1.0f + expf(-x)); }
// jax.lax.top_k ordering: larger value first; ties -> lower flat index
__device__ inline bool better(float v1, int i1, float v2, int i2) {
  return (v1 > v2) || (v1 == v2 && i1 < i2);
}

// Device-scope sense-reversal grid barrier. All NBLK blocks co-resident (see launch config).
// Release chain: each block's tid0 does __threadfence (agent release of its XCD L2) + ACQ_REL
// RMW arrival; last arriver resets cnt then RELEASE-stores gen+1; spinners relaxed-poll then
// ACQUIRE-load gen (invalidates L1/L2 stale lines) before proceeding.
__device__ inline void grid_sync(unsigned* cnt, unsigned* gen) {
  __syncthreads();
  if (threadIdx.x == 0) {
    __threadfence();
    unsigned g = __hip_atomic_load(gen, __ATOMIC_RELAXED, __HIP_MEMORY_SCOPE_AGENT);
    unsigned arr = __hip_atomic_fetch_add(cnt, 1u, __ATOMIC_ACQ_REL, __HIP_MEMORY_SCOPE_AGENT);
    if (arr == NBLK - 1) {
      __hip_atomic_store(cnt, 0u, __ATOMIC_RELAXED, __HIP_MEMORY_SCOPE_AGENT);
      __hip_atomic_store(gen, g + 1u, __ATOMIC_RELEASE, __HIP_MEMORY_SCOPE_AGENT);
    } else {
      while (__hip_atomic_load(gen, __ATOMIC_RELAXED, __HIP_MEMORY_SCOPE_AGENT) == g)
        __builtin_amdgcn_s_sleep(8);
      (void)__hip_atomic_load(gen, __ATOMIC_ACQUIRE, __HIP_MEMORY_SCOPE_AGENT);
    }
  }
  __syncthreads();
}

// ---------------- init (also zeroes the barrier state each replay) ----------------
__global__ __launch_bounds__(256) void init_kernel(
    const float* __restrict__ h0, const float* __restrict__ c0,
    int* __restrict__ tokA, float* __restrict__ scores, int* __restrict__ finished,
    float* __restrict__ h_cur, float* __restrict__ c_cur, float* __restrict__ prev_cur,
    unsigned* __restrict__ bar) {
  int tid = threadIdx.x;
  if (tid < 2) bar[tid] = 0u;
  for (int i = tid; i < KBEAM * TOKW; i += 256)
    tokA[i] = (i % TOKW == 0) ? START_TOK : PAD_TOK;
  if (tid < KBEAM) { scores[tid] = (tid == 0) ? 0.f : NEGF; finished[tid] = 0; }
  for (int i = tid; i < KBEAM * HDIM; i += 256) {
    int e = i & (HDIM - 1);
    h_cur[i] = h0[e]; c_cur[i] = c0[e]; prev_cur[i] = 0.f;
  }
}

// ---------------- keys = enc @ W_attproj^T : (S,H). One wave per output col j. ----------------
__global__ __launch_bounds__(256) void keys_kernel(
    const float* __restrict__ enc, const float* __restrict__ Wap, float* __restrict__ keys) {
  int j = (blockIdx.x * blockDim.x + threadIdx.x) >> 6;  // 0..1023
  int lane = threadIdx.x & 63;
  float w[32];
#pragma unroll
  for (int m = 0; m < 32; ++m) w[m] = Wap[(size_t)j * 2048 + m * 64 + lane];
  for (int s = 0; s < SLEN; ++s) {
    float a = 0.f;
#pragma unroll
    for (int m = 0; m < 32; ++m) a += w[m] * enc[(size_t)s * 2048 + m * 64 + lane];
    float r = wsum(a);
    if (lane == 0) keys[(size_t)s * 1024 + j] = r;
  }
}

// ---------------- persistent kernel: all 70 steps, 6 grid barriers per step ----------------
__global__ __launch_bounds__(256, 2) void step_kernel(
    const float* __restrict__ enc, const float* __restrict__ emb,
    const float* __restrict__ W_ih, const float* __restrict__ b_ih,
    const float* __restrict__ W_hh, const float* __restrict__ b_hh,
    const float* __restrict__ Wc, const float* __restrict__ Wv,
    const float* __restrict__ keys, const int* __restrict__ src_len,
    float* __restrict__ gates, float* __restrict__ h_cur, float* __restrict__ c_cur,
    float* __restrict__ prev_cur, float* __restrict__ h_new, float* __restrict__ c_new,
    float* __restrict__ ctx, float* __restrict__ outb, float* __restrict__ logits,
    float* __restrict__ rt_val, int* __restrict__ rt_idx,
    int* __restrict__ tokA, int* __restrict__ tokB,
    float* __restrict__ scores, int* __restrict__ finished,
    unsigned* __restrict__ bar, float* __restrict__ dout) {
  // LDS (27.6 KB total; 2 blocks/CU -> 55 KB of 160 KB)
  __shared__ float sh_hn[HDIM];     // attn
  __shared__ float sh_esm[SLEN];    // attn
  __shared__ float sh_red[256];     // attn (first 128) + rowtop
  __shared__ float sh_sv[256 * 10]; // rowtop
  __shared__ int   sh_si[256 * 10]; // rowtop
  __shared__ int   sh_last[KBEAM];  // gates token broadcast
  __shared__ float m_wv[10];        // merge
  __shared__ int   m_wrow[10], m_wcol[10], m_ofin[10];
  __shared__ float m_cv[KBEAM * 10];
  __shared__ int   m_ci[KBEAM * 10];

  unsigned* bcnt = bar;
  unsigned* bgen = bar + 1;
  const int bid = blockIdx.x, tid = threadIdx.x;
  const int wv = bid * 4 + (tid >> 6);   // wave id 0..2047
  const int lane = tid & 63;

  int* curp = tokA;
  int* nxtp = tokB;

  for (int t = 0; t < TSTEPS; ++t) {
    // ===== S1: gates = x@W_ih^T + b_ih + h@W_hh^T + b_hh. 2 cols per wave (j0 = wv*2). =====
    {
      if (tid < KBEAM) sh_last[tid] = curp[tid * TOKW + t];
      __syncthreads();
      int last[KBEAM];
#pragma unroll
      for (int k = 0; k < KBEAM; ++k) last[k] = sh_last[k];
      int j0 = wv * 2;
      float acc[2][KBEAM];
#pragma unroll
      for (int jj = 0; jj < 2; ++jj)
#pragma unroll
        for (int k = 0; k < KBEAM; ++k) acc[jj][k] = 0.f;

      const float4* wA = (const float4*)(W_ih + (size_t)j0 * 2048);
      const float4* wB = (const float4*)(W_ih + (size_t)(j0 + 1) * 2048);
      const float4* hA = (const float4*)(W_hh + (size_t)j0 * 1024);
      const float4* hB = (const float4*)(W_hh + (size_t)(j0 + 1) * 1024);
      const float4* emb4 = (const float4*)emb;
      const float4* prev4 = (const float4*)prev_cur;
      const float4* h4 = (const float4*)h_cur;

#pragma unroll
      for (int m = 0; m < 4; ++m) {            // emb part
        int e = m * 64 + lane;
        float4 w0 = wA[e];
        float4 w1 = wB[e];
#pragma unroll
        for (int k = 0; k < KBEAM; ++k) {
          float4 x = emb4[(size_t)last[k] * 256 + e];
          acc[0][k] += w0.x * x.x; acc[0][k] += w0.y * x.y; acc[0][k] += w0.z * x.z; acc[0][k] += w0.w * x.w;
          acc[1][k] += w1.x * x.x; acc[1][k] += w1.y * x.y; acc[1][k] += w1.z * x.z; acc[1][k] += w1.w * x.w;
        }
      }
#pragma unroll
      for (int m = 0; m < 4; ++m) {            // prevOut part
        int e = m * 64 + lane;
        float4 w0 = wA[256 + e];
        float4 w1 = wB[256 + e];
#pragma unroll
        for (int k = 0; k < KBEAM; ++k) {
          float4 x = prev4[k * 256 + e];
          acc[0][k] += w0.x * x.x; acc[0][k] += w0.y * x.y; acc[0][k] += w0.z * x.z; acc[0][k] += w0.w * x.w;
          acc[1][k] += w1.x * x.x; acc[1][k] += w1.y * x.y; acc[1][k] += w1.z * x.z; acc[1][k] += w1.w * x.w;
        }
      }
#pragma unroll
      for (int m = 0; m < 4; ++m) {            // h part
        int e = m * 64 + lane;
        float4 w0 = hA[e];
        float4 w1 = hB[e];
#pragma unroll
        for (int k = 0; k < KBEAM; ++k) {
          float4 x = h4[k * 256 + e];
          acc[0][k] += w0.x * x.x; acc[0][k] += w0.y * x.y; acc[0][k] += w0.z * x.z; acc[0][k] += w0.w * x.w;
          acc[1][k] += w1.x * x.x; acc[1][k] += w1.y * x.y; acc[1][k] += w1.z * x.z; acc[1][k] += w1.w * x.w;
        }
      }
#pragma unroll
      for (int jj = 0; jj < 2; ++jj) {
        int j = j0 + jj;
#pragma unroll
        for (int k = 0; k < KBEAM; ++k) {
          float r = wsum(acc[jj][k]);
          if (lane == 0) gates[k * 4096 + j] = r + b_ih[j] + b_hh[j];
        }
      }
    }
    grid_sync(bcnt, bgen);

    // ===== S2: LSTM elementwise + attention + ctx. Blocks 0..9 (block = beam). =====
    if (bid < KBEAM) {
      int k = bid;
      {
        const float4* g4 = (const float4*)(gates + (size_t)k * 4096);
        float4 gi = g4[tid];
        float4 gf = g4[256 + tid];
        float4 gg = g4[512 + tid];
        float4 go = g4[768 + tid];
        float4 cc = ((const float4*)(c_cur + (size_t)k * HDIM))[tid];
        float4 cn, hv;
        cn.x = sigmoidf(gf.x) * cc.x + sigmoidf(gi.x) * tanhf(gg.x); hv.x = sigmoidf(go.x) * tanhf(cn.x);
        cn.y = sigmoidf(gf.y) * cc.y + sigmoidf(gi.y) * tanhf(gg.y); hv.y = sigmoidf(go.y) * tanhf(cn.y);
        cn.z = sigmoidf(gf.z) * cc.z + sigmoidf(gi.z) * tanhf(gg.z); hv.z = sigmoidf(go.z) * tanhf(cn.z);
        cn.w = sigmoidf(gf.w) * cc.w + sigmoidf(gi.w) * tanhf(gg.w); hv.w = sigmoidf(go.w) * tanhf(cn.w);
        ((float4*)(c_new + (size_t)k * HDIM))[tid] = cn;
        ((float4*)(h_new + (size_t)k * HDIM))[tid] = hv;
        ((float4*)sh_hn)[tid] = hv;
      }
      __syncthreads();

      int sl = src_len[0];
      int w = tid >> 6;
      float hr[16];
#pragma unroll
      for (int m = 0; m < 16; ++m) hr[m] = sh_hn[m * 64 + lane];
      for (int n = 0; n < 32; ++n) {
        int s = w * 32 + n;
        const float* kr = keys + (size_t)s * 1024;
        float p = 0.f;
#pragma unroll
        for (int m = 0; m < 16; ++m) p += kr[m * 64 + lane] * hr[m];
        float r = wsum(p);
        if (lane == 0) sh_esm[s] = (s >= sl) ? NEGF : r;
      }
      __syncthreads();

      if (tid < SLEN) sh_red[tid] = sh_esm[tid];
      __syncthreads();
      for (int off = 64; off >= 1; off >>= 1) {
        if (tid < off) sh_red[tid] = fmaxf(sh_red[tid], sh_red[tid + off]);
        __syncthreads();
      }
      float mx = sh_red[0];
      __syncthreads();
      if (tid < SLEN) { sh_esm[tid] = expf(sh_esm[tid] - mx); sh_red[tid] = sh_esm[tid]; }
      __syncthreads();
      for (int off = 64; off >= 1; off >>= 1) {
        if (tid < off) sh_red[tid] = sh_red[tid] + sh_red[tid + off];
        __syncthreads();
      }
      float inv = 1.0f / sh_red[0];
      __syncthreads();

      const float4* enc4 = (const float4*)enc;
      float4 a0 = make_float4(0.f, 0.f, 0.f, 0.f);
      float4 a1 = make_float4(0.f, 0.f, 0.f, 0.f);
      for (int s = 0; s < SLEN; ++s) {
        float a = sh_esm[s] * inv;
        float4 e0 = enc4[(size_t)s * 512 + tid];
        float4 e1 = enc4[(size_t)s * 512 + 256 + tid];
        a0.x += a * e0.x; a0.y += a * e0.y; a0.z += a * e0.z; a0.w += a * e0.w;
        a1.x += a * e1.x; a1.y += a * e1.y; a1.z += a * e1.z; a1.w += a * e1.w;
      }
      ((float4*)(ctx + (size_t)k * 2048))[tid] = a0;
      ((float4*)(ctx + (size_t)k * 2048))[256 + tid] = a1;
    }
    grid_sync(bcnt, bgen);

    // ===== S3: out = tanh([ctx,h_new] @ W_comb^T). Waves 0..1023 (wave = j). =====
    if (wv < 1024) {
      int j = wv;
      float acc[KBEAM];
#pragma unroll
      for (int k = 0; k < KBEAM; ++k) acc[k] = 0.f;
      const float4* wr4 = (const float4*)(Wc + (size_t)j * 3072);
      const float4* ctx4 = (const float4*)ctx;
      const float4* h4 = (const float4*)h_new;
#pragma unroll
      for (int m = 0; m < 8; ++m) {            // ctx part (512 f4)
        int e = m * 64 + lane;
        float4 w = wr4[e];
#pragma unroll
        for (int k = 0; k < KBEAM; ++k) {
          float4 x = ctx4[k * 512 + e];
          acc[k] += w.x * x.x; acc[k] += w.y * x.y; acc[k] += w.z * x.z; acc[k] += w.w * x.w;
        }
      }
#pragma unroll
      for (int m = 0; m < 4; ++m) {            // h_new part (256 f4)
        int e = m * 64 + lane;
        float4 w = wr4[512 + e];
#pragma unroll
        for (int k = 0; k < KBEAM; ++k) {
          float4 x = h4[k * 256 + e];
          acc[k] += w.x * x.x; acc[k] += w.y * x.y; acc[k] += w.z * x.z; acc[k] += w.w * x.w;
        }
      }
#pragma unroll
      for (int k = 0; k < KBEAM; ++k) {
        float r = wsum(acc[k]);
        if (lane == 0) outb[k * 1024 + j] = tanhf(r);
      }
    }
    grid_sync(bcnt, bgen);

    // ===== S4: logits = out @ W_vocab^T. 16 cols per wave in 4-col chunks. =====
    {
      const float4* ob4 = (const float4*)outb;
      int v0 = wv * 16;
      for (int c = 0; c < 4; ++c) {
        int vb = v0 + c * 4;
        if (vb < VOCAB) {
          float acc[4][KBEAM];
#pragma unroll
          for (int vvv = 0; vvv < 4; ++vvv)
#pragma unroll
            for (int k = 0; k < KBEAM; ++k) acc[vvv][k] = 0.f;
          const float4* w0r = (const float4*)(Wv + (size_t)(vb + 0) * 1024);
          const float4* w1r = (const float4*)(Wv + (size_t)(vb + 1) * 1024);
          const float4* w2r = (const float4*)(Wv + (size_t)(vb + 2) * 1024);
          const float4* w3r = (const float4*)(Wv + (size_t)(vb + 3) * 1024);
#pragma unroll
          for (int m = 0; m < 4; ++m) {
            int e = m * 64 + lane;
            float4 w0 = w0r[e];
            float4 w1 = w1r[e];
            float4 w2 = w2r[e];
            float4 w3 = w3r[e];
#pragma unroll
            for (int k = 0; k < KBEAM; ++k) {
              float4 x = ob4[k * 256 + e];
              acc[0][k] += w0.x * x.x; acc[0][k] += w0.y * x.y; acc[0][k] += w0.z * x.z; acc[0][k] += w0.w * x.w;
              acc[1][k] += w1.x * x.x; acc[1][k] += w1.y * x.y; acc[1][k] += w1.z * x.z; acc[1][k] += w1.w * x.w;
              acc[2][k] += w2.x * x.x; acc[2][k] += w2.y * x.y; acc[2][k] += w2.z * x.z; acc[2][k] += w2.w * x.w;
              acc[3][k] += w3.x * x.x; acc[3][k] += w3.y * x.y; acc[3][k] += w3.z * x.z; acc[3][k] += w3.w * x.w;
            }
          }
#pragma unroll
          for (int vvv = 0; vvv < 4; ++vvv)
#pragma unroll
            for (int k = 0; k < KBEAM; ++k) {
              float r = wsum(acc[vvv][k]);
              if (lane == 0) logits[(size_t)k * VOCAB + vb + vvv] = r;
            }
        }
      }
    }
    grid_sync(bcnt, bgen);

    // ===== S5: per-row log-softmax + row top-10. Blocks 0..9 (block = beam). =====
    if (bid < KBEAM) {
      int k = bid;
      const float* lg = logits + (size_t)k * VOCAB;

      float m = -3.4e38f;
      for (int v = tid; v < VOCAB; v += 256) m = fmaxf(m, lg[v]);
      sh_red[tid] = m;
      __syncthreads();
      for (int off = 128; off >= 1; off >>= 1) {
        if (tid < off) sh_red[tid] = fmaxf(sh_red[tid], sh_red[tid + off]);
        __syncthreads();
      }
      float mx = sh_red[0];
      __syncthreads();

      float s = 0.f;
      for (int v = tid; v < VOCAB; v += 256) s += expf(lg[v] - mx);
      sh_red[tid] = s;
      __syncthreads();
      for (int off = 128; off >= 1; off >>= 1) {
        if (tid < off) sh_red[tid] = sh_red[tid] + sh_red[tid + off];
        __syncthreads();
      }
      float logZ = logf(sh_red[0]);
      __syncthreads();

      bool fin = finished[k] != 0;
      float sk = scores[k];

      float lv[10]; int li[10];
#pragma unroll
      for (int i = 0; i < 10; ++i) { lv[i] = -3.4e38f; li[i] = 0x7fffffff; }
      for (int v = tid; v < VOCAB; v += 256) {
        float val;
        if (fin) {
          val = sk + ((v == PAD_TOK) ? 0.f : NEGF);
        } else {
          float lp = (lg[v] - mx) - logZ;
          val = sk + lp;
        }
        if (better(val, v, lv[9], li[9])) {
          lv[9] = val; li[9] = v;
#pragma unroll
          for (int p = 9; p > 0; --p) {
            if (better(lv[p], li[p], lv[p - 1], li[p - 1])) {
              float tv = lv[p]; lv[p] = lv[p - 1]; lv[p - 1] = tv;
              int ti = li[p]; li[p] = li[p - 1]; li[p - 1] = ti;
            }
          }
        }
      }
#pragma unroll
      for (int i = 0; i < 10; ++i) { sh_sv[tid * 10 + i] = lv[i]; sh_si[tid * 10 + i] = li[i]; }
      __syncthreads();

      for (int off = 128; off >= 1; off >>= 1) {
        if (tid < off) {
          int ia = 0, ib = 0;
          float ov[10]; int oi[10];
#pragma unroll
          for (int i = 0; i < 10; ++i) {
            float av = sh_sv[tid * 10 + ia];         int aii = sh_si[tid * 10 + ia];
            float bvv = sh_sv[(tid + off) * 10 + ib]; int bii = sh_si[(tid + off) * 10 + ib];
            if (better(av, aii, bvv, bii)) { ov[i] = av; oi[i] = aii; ++ia; }
            else                           { ov[i] = bvv; oi[i] = bii; ++ib; }
          }
#pragma unroll
          for (int i = 0; i < 10; ++i) { sh_sv[tid * 10 + i] = ov[i]; sh_si[tid * 10 + i] = oi[i]; }
        }
        __syncthreads();
      }
      if (tid < 10) {
        rt_val[k * 10 + tid] = sh_sv[tid];
        rt_idx[k * 10 + tid] = k * VOCAB + sh_si[tid];
      }
    }
    grid_sync(bcnt, bgen);

    // ===== S6: merge 100 candidates + beam-state update. Block 0. =====
    if (bid == 0) {
      if (tid < KBEAM) m_ofin[tid] = finished[tid];
      if (tid < KBEAM * 10) { m_cv[tid] = rt_val[tid]; m_ci[tid] = rt_idx[tid]; }
      __syncthreads();
      if (tid == 0) {
        float bv[10]; int bi[10];
#pragma unroll
        for (int i = 0; i < 10; ++i) { bv[i] = -3.4e38f; bi[i] = 0x7fffffff; }
        for (int i = 0; i < KBEAM * 10; ++i) {
          float v = m_cv[i]; int g = m_ci[i];
          if (better(v, g, bv[9], bi[9])) {
            bv[9] = v; bi[9] = g;
#pragma unroll
            for (int p = 9; p > 0; --p) {
              if (better(bv[p], bi[p], bv[p - 1], bi[p - 1])) {
                float tv = bv[p]; bv[p] = bv[p - 1]; bv[p - 1] = tv;
                int ti = bi[p]; bi[p] = bi[p - 1]; bi[p - 1] = ti;
              }
            }
          }
        }
#pragma unroll
        for (int i = 0; i < 10; ++i) { m_wv[i] = bv[i]; m_wrow[i] = bi[i] / VOCAB; m_wcol[i] = bi[i] % VOCAB; }
      }
      __syncthreads();
      if (tid < KBEAM) {
        scores[tid] = m_wv[tid];
        finished[tid] = (m_ofin[m_wrow[tid]] || (m_wcol[tid] == EOS_TOK)) ? 1 : 0;
      }
      for (int i = tid; i < KBEAM * TOKW; i += 256) {
        int kk = i / TOKW, j = i % TOKW;
        nxtp[i] = (j == t + 1) ? m_wcol[kk] : curp[m_wrow[kk] * TOKW + j];
      }
      const float4* h4n = (const float4*)h_new;
      const float4* c4n = (const float4*)c_new;
      const float4* o4 = (const float4*)outb;
      float4* h4c = (float4*)h_cur;
      float4* c4c = (float4*)c_cur;
      float4* p4c = (float4*)prev_cur;
      for (int i = tid; i < KBEAM * 256; i += 256) {
        int kk = i >> 8, e = i & 255;
        int r = m_wrow[kk];
        h4c[i] = h4n[r * 256 + e];
        c4c[i] = c4n[r * 256 + e];
        p4c[i] = o4[r * 256 + e];
      }
    }
    grid_sync(bcnt, bgen);

    int* tmp = curp; curp = nxtp; nxtp = tmp;
  }

  // ===== writeout (block 0) =====
  if (bid == 0) {
    for (int i = tid; i < KBEAM * TOKW; i += 256) dout[i] = (float)curp[i];
    if (tid < KBEAM) dout[KBEAM * TOKW + tid] = scores[tid];
  }
}

extern "C" void kernel_launch(void* const* d_in, const int* in_sizes, int n_in,
                              void* d_out, int out_size, void* d_ws, size_t ws_size,
                              hipStream_t stream) {
  const float* enc  = (const float*)d_in[0];
  const float* h0   = (const float*)d_in[1];
  const float* c0   = (const float*)d_in[2];
  const float* emb  = (const float*)d_in[3];
  const float* W_ih = (const float*)d_in[4];
  const float* b_ih = (const float*)d_in[5];
  const float* W_hh = (const float*)d_in[6];
  const float* b_hh = (const float*)d_in[7];
  const float* Wap  = (const float*)d_in[8];
  const float* Wc   = (const float*)d_in[9];
  const float* Wv   = (const float*)d_in[10];
  const int* src_len = (const int*)d_in[11];

  char* ws = (char*)d_ws;
  size_t off = 0;
  auto alloc = [&](size_t bytes) -> void* {
    void* p = ws + off;
    off += (bytes + 255) & ~(size_t)255;
    return p;
  };
  float* keys     = (float*)alloc((size_t)SLEN * HDIM * 4);
  float* gates    = (float*)alloc((size_t)KBEAM * 4096 * 4);
  float* h_cur    = (float*)alloc((size_t)KBEAM * HDIM * 4);
  float* c_cur    = (float*)alloc((size_t)KBEAM * HDIM * 4);
  float* prev_cur = (float*)alloc((size_t)KBEAM * HDIM * 4);
  float* h_new    = (float*)alloc((size_t)KBEAM * HDIM * 4);
  float* c_new    = (float*)alloc((size_t)KBEAM * HDIM * 4);
  float* ctx      = (float*)alloc((size_t)KBEAM * 2048 * 4);
  float* outb     = (float*)alloc((size_t)KBEAM * HDIM * 4);
  float* logits   = (float*)alloc((size_t)KBEAM * VOCAB * 4);
  float* rt_val   = (float*)alloc((size_t)KBEAM * 10 * 4);
  int*   rt_idx   = (int*)  alloc((size_t)KBEAM * 10 * 4);
  int*   tokA     = (int*)  alloc((size_t)KBEAM * TOKW * 4);
  int*   tokB     = (int*)  alloc((size_t)KBEAM * TOKW * 4);
  float* scores   = (float*)alloc((size_t)KBEAM * 4);
  int*   finished = (int*)  alloc((size_t)KBEAM * 4);
  unsigned* bar   = (unsigned*)alloc(2 * 4);
  (void)ws_size; (void)in_sizes; (void)n_in; (void)out_size;

  init_kernel<<<1, 256, 0, stream>>>(h0, c0, tokA, scores, finished, h_cur, c_cur, prev_cur, bar);
  keys_kernel<<<256, 256, 0, stream>>>(enc, Wap, keys);

  step_kernel<<<NBLK, 256, 0, stream>>>(
      enc, emb, W_ih, b_ih, W_hh, b_hh, Wc, Wv, keys, src_len,
      gates, h_cur, c_cur, prev_cur, h_new, c_new, ctx, outb, logits,
      rt_val, rt_idx, tokA, tokB, scores, finished, bar, (float*)d_out);
}

// Round 5
// 59413.055 us; speedup vs baseline: 1.3963x; 1.3963x over previous
//
#include <hip/hip_runtime.h>
#include <math.h>

#define KBEAM 10
#define TSTEPS 70
#define EOS_TOK 2
#define PAD_TOK 0
#define START_TOK 1
#define EDIM 1024
#define HDIM 1024
#define VOCAB 32000
#define SLEN 128
#define NEGF (-1000000000.0f)
#define TOKW (TSTEPS + 1)   // 71
#define NBLK 512            // 2 blocks/CU x 256 CUs, co-resident by construction
#define NGRP 8
#define GRPSZ (NBLK / NGRP) // 64

__device__ inline float wsum(float v) {
#pragma unroll
  for (int m = 32; m; m >>= 1) v += __shfl_xor(v, m, 64);
  return v;
}
__device__ inline float sigmoidf(float x) { return 1.0f / (1.0f + expf(-x)); }
__device__ inline bool better(float v1, int i1, float v2, int i2) {
  return (v1 > v2) || (v1 == v2 && i1 < i2);
}

// L3-coherent (agent-scope, relaxed) accesses: bypass stale L2, emit NO cache flushes.
__device__ inline float gloadf(const float* p) {
  return __hip_atomic_load(p, __ATOMIC_RELAXED, __HIP_MEMORY_SCOPE_AGENT);
}
__device__ inline void gstoref(float* p, float v) {
  __hip_atomic_store(p, v, __ATOMIC_RELAXED, __HIP_MEMORY_SCOPE_AGENT);
}
__device__ inline int gloadi(const int* p) {
  return __hip_atomic_load(p, __ATOMIC_RELAXED, __HIP_MEMORY_SCOPE_AGENT);
}
__device__ inline void gstorei(int* p, int v) {
  __hip_atomic_store(p, v, __ATOMIC_RELAXED, __HIP_MEMORY_SCOPE_AGENT);
}

// Two-level tree barrier, relaxed atomics only (data coherence is per-access above).
// bar layout (unsigned, 64-word = 256B spacing): [g*64]=gcnt, [(8+g)*64]=ggen,
// [16*64]=rcnt, [17*64]=rgen. Monotone epochs: no resets, no ABA.
__device__ inline void grid_sync(unsigned* bar, unsigned epoch) {
  __syncthreads();   // drains vmcnt(0): all this block's gstores are at L3 before arrival
  if (threadIdx.x == 0) {
    int g = blockIdx.x & (NGRP - 1);
    unsigned* gcnt = bar + g * 64;
    unsigned* ggen = bar + (NGRP + g) * 64;
    unsigned* rcnt = bar + (2 * NGRP) * 64;
    unsigned* rgen = bar + (2 * NGRP + 1) * 64;
    unsigned old = __hip_atomic_fetch_add(gcnt, 1u, __ATOMIC_RELAXED, __HIP_MEMORY_SCOPE_AGENT);
    if (old == epoch * GRPSZ + (GRPSZ - 1)) {            // group leader
      unsigned ro = __hip_atomic_fetch_add(rcnt, 1u, __ATOMIC_RELAXED, __HIP_MEMORY_SCOPE_AGENT);
      if (ro == epoch * NGRP + (NGRP - 1)) {             // root leader
        __hip_atomic_store(rgen, epoch + 1u, __ATOMIC_RELAXED, __HIP_MEMORY_SCOPE_AGENT);
      } else {
        while (__hip_atomic_load(rgen, __ATOMIC_RELAXED, __HIP_MEMORY_SCOPE_AGENT) <= epoch)
          __builtin_amdgcn_s_sleep(2);
      }
      __hip_atomic_store(ggen, epoch + 1u, __ATOMIC_RELAXED, __HIP_MEMORY_SCOPE_AGENT);
    } else {
      while (__hip_atomic_load(ggen, __ATOMIC_RELAXED, __HIP_MEMORY_SCOPE_AGENT) <= epoch)
        __builtin_amdgcn_s_sleep(2);
    }
  }
  __syncthreads();
}

// ---------------- init (zeroes barrier state each graph replay) ----------------
__global__ __launch_bounds__(256) void init_kernel(
    const float* __restrict__ h0, const float* __restrict__ c0,
    int* __restrict__ tokA, float* __restrict__ scores, int* __restrict__ finished,
    float* __restrict__ h_cur, float* __restrict__ c_cur, float* __restrict__ prev_cur,
    unsigned* __restrict__ bar) {
  int tid = threadIdx.x;
  for (int i = tid; i < 18 * 64; i += 256) bar[i] = 0u;
  for (int i = tid; i < KBEAM * TOKW; i += 256)
    tokA[i] = (i % TOKW == 0) ? START_TOK : PAD_TOK;
  if (tid < KBEAM) { scores[tid] = (tid == 0) ? 0.f : NEGF; finished[tid] = 0; }
  for (int i = tid; i < KBEAM * HDIM; i += 256) {
    int e = i & (HDIM - 1);
    h_cur[i] = h0[e]; c_cur[i] = c0[e]; prev_cur[i] = 0.f;
  }
}

// ---------------- keys = enc @ W_attproj^T : (S,H). One wave per output col j. ----------------
__global__ __launch_bounds__(256) void keys_kernel(
    const float* __restrict__ enc, const float* __restrict__ Wap, float* __restrict__ keys) {
  int j = (blockIdx.x * blockDim.x + threadIdx.x) >> 6;  // 0..1023
  int lane = threadIdx.x & 63;
  float w[32];
#pragma unroll
  for (int m = 0; m < 32; ++m) w[m] = Wap[(size_t)j * 2048 + m * 64 + lane];
  for (int s = 0; s < SLEN; ++s) {
    float a = 0.f;
#pragma unroll
    for (int m = 0; m < 32; ++m) a += w[m] * enc[(size_t)s * 2048 + m * 64 + lane];
    float r = wsum(a);
    if (lane == 0) keys[(size_t)s * 1024 + j] = r;
  }
}

// ---------------- persistent kernel: all 70 steps, fence-free coherence ----------------
__global__ __launch_bounds__(256, 2) void step_kernel(
    const float* __restrict__ enc, const float* __restrict__ emb,
    const float* __restrict__ W_ih, const float* __restrict__ b_ih,
    const float* __restrict__ W_hh, const float* __restrict__ b_hh,
    const float* __restrict__ Wc, const float* __restrict__ Wv,
    const float* __restrict__ keys, const int* __restrict__ src_len,
    float* __restrict__ gates, float* __restrict__ h_cur, float* __restrict__ c_cur,
    float* __restrict__ prev_cur, float* __restrict__ h_new, float* __restrict__ c_new,
    float* __restrict__ ctx, float* __restrict__ outb, float* __restrict__ logits,
    float* __restrict__ rt_val, int* __restrict__ rt_idx,
    int* __restrict__ tokA, int* __restrict__ tokB,
    float* __restrict__ scores, int* __restrict__ finished,
    unsigned* __restrict__ bar, float* __restrict__ dout) {
  __shared__ __align__(16) float sh_x[10240];  // 40KB staging (S1/S3/S4; aliased sv/si in S5)
  __shared__ float sh_hn[HDIM];
  __shared__ float sh_esm[SLEN];
  __shared__ float sh_red[256];
  __shared__ int   sh_last[KBEAM];
  __shared__ float m_wv[10];
  __shared__ int   m_wrow[10], m_wcol[10], m_ofin[10];
  __shared__ float m_cv[100];
  __shared__ int   m_ci[100];

  const int bid = blockIdx.x, tid = threadIdx.x;
  const int wvid = bid * 4 + (tid >> 6);   // 0..2047
  const int lane = tid & 63;
  const float4* sx4 = (const float4*)sh_x;
  unsigned epoch = 0;

  int* curp = tokA;
  int* nxtp = tokB;

  for (int t = 0; t < TSTEPS; ++t) {
    // ===== S1: gates. 2 cols/wave (j0 = wvid*2). Activations LDS-staged in 3 passes. =====
    {
      if (tid < KBEAM) sh_last[tid] = gloadi(curp + tid * TOKW + t);
      __syncthreads();
      const int j0 = wvid * 2;
      float acc0[KBEAM], acc1[KBEAM];
#pragma unroll
      for (int k = 0; k < KBEAM; ++k) { acc0[k] = 0.f; acc1[k] = 0.f; }
      const float4* wA = (const float4*)(W_ih + (size_t)j0 * 2048);
      const float4* wB = wA + 512;
      const float4* hA = (const float4*)(W_hh + (size_t)j0 * 1024);
      const float4* hB = hA + 256;

      // pass 1: emb[last[k]] (read-only input -> plain cached loads)
      for (int f = tid; f < 10240; f += 256) {
        int k = f >> 10, i = f & 1023;
        sh_x[f] = emb[(size_t)sh_last[k] * 1024 + i];
      }
      __syncthreads();
#pragma unroll
      for (int m = 0; m < 4; ++m) {
        int e = m * 64 + lane;
        float4 w0 = wA[e], w1 = wB[e];
#pragma unroll
        for (int k = 0; k < KBEAM; ++k) {
          float4 x = sx4[k * 256 + e];
          acc0[k] += w0.x * x.x; acc0[k] += w0.y * x.y; acc0[k] += w0.z * x.z; acc0[k] += w0.w * x.w;
          acc1[k] += w1.x * x.x; acc1[k] += w1.y * x.y; acc1[k] += w1.z * x.z; acc1[k] += w1.w * x.w;
        }
      }
      __syncthreads();
      // pass 2: prevOut
      for (int f = tid; f < 10240; f += 256) sh_x[f] = gloadf(prev_cur + f);
      __syncthreads();
#pragma unroll
      for (int m = 0; m < 4; ++m) {
        int e = m * 64 + lane;
        float4 w0 = wA[256 + e], w1 = wB[256 + e];
#pragma unroll
        for (int k = 0; k < KBEAM; ++k) {
          float4 x = sx4[k * 256 + e];
          acc0[k] += w0.x * x.x; acc0[k] += w0.y * x.y; acc0[k] += w0.z * x.z; acc0[k] += w0.w * x.w;
          acc1[k] += w1.x * x.x; acc1[k] += w1.y * x.y; acc1[k] += w1.z * x.z; acc1[k] += w1.w * x.w;
        }
      }
      __syncthreads();
      // pass 3: h
      for (int f = tid; f < 10240; f += 256) sh_x[f] = gloadf(h_cur + f);
      __syncthreads();
#pragma unroll
      for (int m = 0; m < 4; ++m) {
        int e = m * 64 + lane;
        float4 w0 = hA[e], w1 = hB[e];
#pragma unroll
        for (int k = 0; k < KBEAM; ++k) {
          float4 x = sx4[k * 256 + e];
          acc0[k] += w0.x * x.x; acc0[k] += w0.y * x.y; acc0[k] += w0.z * x.z; acc0[k] += w0.w * x.w;
          acc1[k] += w1.x * x.x; acc1[k] += w1.y * x.y; acc1[k] += w1.z * x.z; acc1[k] += w1.w * x.w;
        }
      }
#pragma unroll
      for (int k = 0; k < KBEAM; ++k) {
        float r = wsum(acc0[k]);
        if (lane == 0) gstoref(&gates[k * 4096 + j0], r + b_ih[j0] + b_hh[j0]);
      }
#pragma unroll
      for (int k = 0; k < KBEAM; ++k) {
        float r = wsum(acc1[k]);
        if (lane == 0) gstoref(&gates[k * 4096 + j0 + 1], r + b_ih[j0 + 1] + b_hh[j0 + 1]);
      }
    }
    grid_sync(bar, epoch); ++epoch;

    // ===== S2: LSTM elementwise + attention + ctx. Blocks 0..9. =====
    if (bid < KBEAM) {
      int k = bid;
      {
        const float* g = gates + (size_t)k * 4096;
        const float* cc = c_cur + (size_t)k * HDIM;
        float4 gi = make_float4(gloadf(g + tid * 4 + 0), gloadf(g + tid * 4 + 1),
                                gloadf(g + tid * 4 + 2), gloadf(g + tid * 4 + 3));
        float4 gf = make_float4(gloadf(g + 1024 + tid * 4 + 0), gloadf(g + 1024 + tid * 4 + 1),
                                gloadf(g + 1024 + tid * 4 + 2), gloadf(g + 1024 + tid * 4 + 3));
        float4 gg = make_float4(gloadf(g + 2048 + tid * 4 + 0), gloadf(g + 2048 + tid * 4 + 1),
                                gloadf(g + 2048 + tid * 4 + 2), gloadf(g + 2048 + tid * 4 + 3));
        float4 go = make_float4(gloadf(g + 3072 + tid * 4 + 0), gloadf(g + 3072 + tid * 4 + 1),
                                gloadf(g + 3072 + tid * 4 + 2), gloadf(g + 3072 + tid * 4 + 3));
        float4 ccv = make_float4(gloadf(cc + tid * 4 + 0), gloadf(cc + tid * 4 + 1),
                                 gloadf(cc + tid * 4 + 2), gloadf(cc + tid * 4 + 3));
        float4 cn, hv;
        cn.x = sigmoidf(gf.x) * ccv.x + sigmoidf(gi.x) * tanhf(gg.x); hv.x = sigmoidf(go.x) * tanhf(cn.x);
        cn.y = sigmoidf(gf.y) * ccv.y + sigmoidf(gi.y) * tanhf(gg.y); hv.y = sigmoidf(go.y) * tanhf(cn.y);
        cn.z = sigmoidf(gf.z) * ccv.z + sigmoidf(gi.z) * tanhf(gg.z); hv.z = sigmoidf(go.z) * tanhf(cn.z);
        cn.w = sigmoidf(gf.w) * ccv.w + sigmoidf(gi.w) * tanhf(gg.w); hv.w = sigmoidf(go.w) * tanhf(cn.w);
        float* cnp = c_new + (size_t)k * HDIM + tid * 4;
        float* hnp = h_new + (size_t)k * HDIM + tid * 4;
        gstoref(cnp + 0, cn.x); gstoref(cnp + 1, cn.y); gstoref(cnp + 2, cn.z); gstoref(cnp + 3, cn.w);
        gstoref(hnp + 0, hv.x); gstoref(hnp + 1, hv.y); gstoref(hnp + 2, hv.z); gstoref(hnp + 3, hv.w);
        ((float4*)sh_hn)[tid] = hv;
      }
      __syncthreads();

      int sl = src_len[0];
      int w = tid >> 6;
      float hr[16];
#pragma unroll
      for (int m = 0; m < 16; ++m) hr[m] = sh_hn[m * 64 + lane];
      for (int n = 0; n < 32; ++n) {
        int s = w * 32 + n;
        const float* kr = keys + (size_t)s * 1024;
        float p = 0.f;
#pragma unroll
        for (int m = 0; m < 16; ++m) p += kr[m * 64 + lane] * hr[m];
        float r = wsum(p);
        if (lane == 0) sh_esm[s] = (s >= sl) ? NEGF : r;
      }
      __syncthreads();

      if (tid < SLEN) sh_red[tid] = sh_esm[tid];
      __syncthreads();
      for (int off = 64; off >= 1; off >>= 1) {
        if (tid < off) sh_red[tid] = fmaxf(sh_red[tid], sh_red[tid + off]);
        __syncthreads();
      }
      float mx = sh_red[0];
      __syncthreads();
      if (tid < SLEN) { sh_esm[tid] = expf(sh_esm[tid] - mx); sh_red[tid] = sh_esm[tid]; }
      __syncthreads();
      for (int off = 64; off >= 1; off >>= 1) {
        if (tid < off) sh_red[tid] = sh_red[tid] + sh_red[tid + off];
        __syncthreads();
      }
      float inv = 1.0f / sh_red[0];
      __syncthreads();

      const float4* enc4 = (const float4*)enc;
      float4 a0 = make_float4(0.f, 0.f, 0.f, 0.f);
      float4 a1 = make_float4(0.f, 0.f, 0.f, 0.f);
      for (int s = 0; s < SLEN; ++s) {
        float a = sh_esm[s] * inv;
        float4 e0 = enc4[(size_t)s * 512 + tid];
        float4 e1 = enc4[(size_t)s * 512 + 256 + tid];
        a0.x += a * e0.x; a0.y += a * e0.y; a0.z += a * e0.z; a0.w += a * e0.w;
        a1.x += a * e1.x; a1.y += a * e1.y; a1.z += a * e1.z; a1.w += a * e1.w;
      }
      float* cp = ctx + (size_t)k * 2048 + tid * 4;
      gstoref(cp + 0, a0.x); gstoref(cp + 1, a0.y); gstoref(cp + 2, a0.z); gstoref(cp + 3, a0.w);
      gstoref(cp + 1024, a1.x); gstoref(cp + 1025, a1.y); gstoref(cp + 1026, a1.z); gstoref(cp + 1027, a1.w);
    }
    grid_sync(bar, epoch); ++epoch;

    // ===== S3: out = tanh([ctx,h_new] @ W_comb^T). Blocks 0..255, wave = j. 3 LDS passes. =====
    if (bid < 256) {
      int j = wvid;  // 0..1023
      float acc[KBEAM];
#pragma unroll
      for (int k = 0; k < KBEAM; ++k) acc[k] = 0.f;
      const float4* wr4 = (const float4*)(Wc + (size_t)j * 3072);
      // pass 1: ctx cols [0,1024)
      for (int f = tid; f < 10240; f += 256) {
        int k = f >> 10, i = f & 1023;
        sh_x[f] = gloadf(ctx + (size_t)k * 2048 + i);
      }
      __syncthreads();
#pragma unroll
      for (int m = 0; m < 4; ++m) {
        int e = m * 64 + lane;
        float4 wq = wr4[e];
#pragma unroll
        for (int k = 0; k < KBEAM; ++k) {
          float4 x = sx4[k * 256 + e];
          acc[k] += wq.x * x.x; acc[k] += wq.y * x.y; acc[k] += wq.z * x.z; acc[k] += wq.w * x.w;
        }
      }
      __syncthreads();
      // pass 2: ctx cols [1024,2048)
      for (int f = tid; f < 10240; f += 256) {
        int k = f >> 10, i = f & 1023;
        sh_x[f] = gloadf(ctx + (size_t)k * 2048 + 1024 + i);
      }
      __syncthreads();
#pragma unroll
      for (int m = 0; m < 4; ++m) {
        int e = m * 64 + lane;
        float4 wq = wr4[256 + e];
#pragma unroll
        for (int k = 0; k < KBEAM; ++k) {
          float4 x = sx4[k * 256 + e];
          acc[k] += wq.x * x.x; acc[k] += wq.y * x.y; acc[k] += wq.z * x.z; acc[k] += wq.w * x.w;
        }
      }
      __syncthreads();
      // pass 3: h_new
      for (int f = tid; f < 10240; f += 256) sh_x[f] = gloadf(h_new + f);
      __syncthreads();
#pragma unroll
      for (int m = 0; m < 4; ++m) {
        int e = m * 64 + lane;
        float4 wq = wr4[512 + e];
#pragma unroll
        for (int k = 0; k < KBEAM; ++k) {
          float4 x = sx4[k * 256 + e];
          acc[k] += wq.x * x.x; acc[k] += wq.y * x.y; acc[k] += wq.z * x.z; acc[k] += wq.w * x.w;
        }
      }
#pragma unroll
      for (int k = 0; k < KBEAM; ++k) {
        float r = wsum(acc[k]);
        if (lane == 0) gstoref(&outb[k * 1024 + j], tanhf(r));
      }
    }
    grid_sync(bar, epoch); ++epoch;

    // ===== S4: logits = out @ W_vocab^T. 16 cols/wave in 4-col chunks; outb LDS-staged. =====
    {
      for (int f = tid; f < 10240; f += 256) sh_x[f] = gloadf(outb + f);
      __syncthreads();
      int v0g = wvid * 16;
      for (int c = 0; c < 4; ++c) {
        int vb = v0g + c * 4;
        if (vb < VOCAB) {
          float acc[4][KBEAM];
#pragma unroll
          for (int vv = 0; vv < 4; ++vv)
#pragma unroll
            for (int k = 0; k < KBEAM; ++k) acc[vv][k] = 0.f;
          const float4* w0r = (const float4*)(Wv + (size_t)(vb + 0) * 1024);
          const float4* w1r = (const float4*)(Wv + (size_t)(vb + 1) * 1024);
          const float4* w2r = (const float4*)(Wv + (size_t)(vb + 2) * 1024);
          const float4* w3r = (const float4*)(Wv + (size_t)(vb + 3) * 1024);
#pragma unroll
          for (int m = 0; m < 4; ++m) {
            int e = m * 64 + lane;
            float4 w0 = w0r[e], w1 = w1r[e], w2 = w2r[e], w3 = w3r[e];
#pragma unroll
            for (int k = 0; k < KBEAM; ++k) {
              float4 x = sx4[k * 256 + e];
              acc[0][k] += w0.x * x.x; acc[0][k] += w0.y * x.y; acc[0][k] += w0.z * x.z; acc[0][k] += w0.w * x.w;
              acc[1][k] += w1.x * x.x; acc[1][k] += w1.y * x.y; acc[1][k] += w1.z * x.z; acc[1][k] += w1.w * x.w;
              acc[2][k] += w2.x * x.x; acc[2][k] += w2.y * x.y; acc[2][k] += w2.z * x.z; acc[2][k] += w2.w * x.w;
              acc[3][k] += w3.x * x.x; acc[3][k] += w3.y * x.y; acc[3][k] += w3.z * x.z; acc[3][k] += w3.w * x.w;
            }
          }
#pragma unroll
          for (int vv = 0; vv < 4; ++vv)
#pragma unroll
            for (int k = 0; k < KBEAM; ++k) {
              float r = wsum(acc[vv][k]);
              if (lane == 0) gstoref(&logits[(size_t)k * VOCAB + vb + vv], r);
            }
        }
      }
    }
    grid_sync(bar, epoch); ++epoch;

    // ===== S5: log-softmax + row top-10. Blocks 0..9. sv/si alias sh_x. =====
    if (bid < KBEAM) {
      int k = bid;
      const float* lg = logits + (size_t)k * VOCAB;
      float* sv = sh_x;
      int* si = (int*)sh_x + 2560;

      float m = -3.4e38f;
      for (int v = tid; v < VOCAB; v += 256) m = fmaxf(m, gloadf(lg + v));
      sh_red[tid] = m;
      __syncthreads();
      for (int off = 128; off >= 1; off >>= 1) {
        if (tid < off) sh_red[tid] = fmaxf(sh_red[tid], sh_red[tid + off]);
        __syncthreads();
      }
      float mx = sh_red[0];
      __syncthreads();

      float s = 0.f;
      for (int v = tid; v < VOCAB; v += 256) s += expf(gloadf(lg + v) - mx);
      sh_red[tid] = s;
      __syncthreads();
      for (int off = 128; off >= 1; off >>= 1) {
        if (tid < off) sh_red[tid] = sh_red[tid] + sh_red[tid + off];
        __syncthreads();
      }
      float logZ = logf(sh_red[0]);
      __syncthreads();

      bool fin = gloadi(finished + k) != 0;
      float sk = gloadf(scores + k);

      float lv[10]; int li[10];
#pragma unroll
      for (int i = 0; i < 10; ++i) { lv[i] = -3.4e38f; li[i] = 0x7fffffff; }
      for (int v = tid; v < VOCAB; v += 256) {
        float val;
        if (fin) {
          val = sk + ((v == PAD_TOK) ? 0.f : NEGF);
        } else {
          float lp = (gloadf(lg + v) - mx) - logZ;
          val = sk + lp;
        }
        if (better(val, v, lv[9], li[9])) {
          lv[9] = val; li[9] = v;
#pragma unroll
          for (int p = 9; p > 0; --p) {
            if (better(lv[p], li[p], lv[p - 1], li[p - 1])) {
              float tv = lv[p]; lv[p] = lv[p - 1]; lv[p - 1] = tv;
              int ti = li[p]; li[p] = li[p - 1]; li[p - 1] = ti;
            }
          }
        }
      }
#pragma unroll
      for (int i = 0; i < 10; ++i) { sv[tid * 10 + i] = lv[i]; si[tid * 10 + i] = li[i]; }
      __syncthreads();

      for (int off = 128; off >= 1; off >>= 1) {
        if (tid < off) {
          int ia = 0, ib = 0;
          float ov[10]; int oi[10];
#pragma unroll
          for (int i = 0; i < 10; ++i) {
            float av = sv[tid * 10 + ia];          int aii = si[tid * 10 + ia];
            float bvv = sv[(tid + off) * 10 + ib]; int bii = si[(tid + off) * 10 + ib];
            if (better(av, aii, bvv, bii)) { ov[i] = av; oi[i] = aii; ++ia; }
            else                           { ov[i] = bvv; oi[i] = bii; ++ib; }
          }
#pragma unroll
          for (int i = 0; i < 10; ++i) { sv[tid * 10 + i] = ov[i]; si[tid * 10 + i] = oi[i]; }
        }
        __syncthreads();
      }
      if (tid < 10) {
        gstoref(&rt_val[k * 10 + tid], sv[tid]);
        gstorei(&rt_idx[k * 10 + tid], k * VOCAB + si[tid]);
      }
    }
    grid_sync(bar, epoch); ++epoch;

    // ===== S6: merge 100 candidates + beam-state update. Block 0. =====
    if (bid == 0) {
      if (tid < KBEAM) m_ofin[tid] = gloadi(finished + tid);
      if (tid < KBEAM * 10) { m_cv[tid] = gloadf(rt_val + tid); m_ci[tid] = gloadi(rt_idx + tid); }
      __syncthreads();
      if (tid == 0) {
        float bv[10]; int bi[10];
#pragma unroll
        for (int i = 0; i < 10; ++i) { bv[i] = -3.4e38f; bi[i] = 0x7fffffff; }
        for (int i = 0; i < KBEAM * 10; ++i) {
          float v = m_cv[i]; int g = m_ci[i];
          if (better(v, g, bv[9], bi[9])) {
            bv[9] = v; bi[9] = g;
#pragma unroll
            for (int p = 9; p > 0; --p) {
              if (better(bv[p], bi[p], bv[p - 1], bi[p - 1])) {
                float tv = bv[p]; bv[p] = bv[p - 1]; bv[p - 1] = tv;
                int ti = bi[p]; bi[p] = bi[p - 1]; bi[p - 1] = ti;
              }
            }
          }
        }
#pragma unroll
        for (int i = 0; i < 10; ++i) { m_wv[i] = bv[i]; m_wrow[i] = bi[i] / VOCAB; m_wcol[i] = bi[i] % VOCAB; }
      }
      __syncthreads();
      if (tid < KBEAM) {
        gstoref(scores + tid, m_wv[tid]);
        gstorei(finished + tid, (m_ofin[m_wrow[tid]] || (m_wcol[tid] == EOS_TOK)) ? 1 : 0);
      }
      for (int i = tid; i < KBEAM * TOKW; i += 256) {
        int kk = i / TOKW, j = i % TOKW;
        int vtok = (j == t + 1) ? m_wcol[kk] : gloadi(curp + m_wrow[kk] * TOKW + j);
        gstorei(nxtp + i, vtok);
      }
      for (int i = tid; i < KBEAM * 1024; i += 256) {
        int kk = i >> 10, e = i & 1023;
        int r = m_wrow[kk];
        gstoref(h_cur + i, gloadf(h_new + r * 1024 + e));
        gstoref(c_cur + i, gloadf(c_new + r * 1024 + e));
        gstoref(prev_cur + i, gloadf(outb + r * 1024 + e));
      }
    }
    grid_sync(bar, epoch); ++epoch;

    int* tmp = curp; curp = nxtp; nxtp = tmp;
  }

  // ===== writeout (block 0) =====
  if (bid == 0) {
    for (int i = tid; i < KBEAM * TOKW; i += 256) dout[i] = (float)gloadi(curp + i);
    if (tid < KBEAM) dout[KBEAM * TOKW + tid] = gloadf(scores + tid);
  }
}

extern "C" void kernel_launch(void* const* d_in, const int* in_sizes, int n_in,
                              void* d_out, int out_size, void* d_ws, size_t ws_size,
                              hipStream_t stream) {
  const float* enc  = (const float*)d_in[0];
  const float* h0   = (const float*)d_in[1];
  const float* c0   = (const float*)d_in[2];
  const float* emb  = (const float*)d_in[3];
  const float* W_ih = (const float*)d_in[4];
  const float* b_ih = (const float*)d_in[5];
  const float* W_hh = (const float*)d_in[6];
  const float* b_hh = (const float*)d_in[7];
  const float* Wap  = (const float*)d_in[8];
  const float* Wc   = (const float*)d_in[9];
  const float* Wv   = (const float*)d_in[10];
  const int* src_len = (const int*)d_in[11];

  char* ws = (char*)d_ws;
  size_t off = 0;
  auto alloc = [&](size_t bytes) -> void* {
    void* p = ws + off;
    off += (bytes + 255) & ~(size_t)255;
    return p;
  };
  float* keys     = (float*)alloc((size_t)SLEN * HDIM * 4);
  float* gates    = (float*)alloc((size_t)KBEAM * 4096 * 4);
  float* h_cur    = (float*)alloc((size_t)KBEAM * HDIM * 4);
  float* c_cur    = (float*)alloc((size_t)KBEAM * HDIM * 4);
  float* prev_cur = (float*)alloc((size_t)KBEAM * HDIM * 4);
  float* h_new    = (float*)alloc((size_t)KBEAM * HDIM * 4);
  float* c_new    = (float*)alloc((size_t)KBEAM * HDIM * 4);
  float* ctx      = (float*)alloc((size_t)KBEAM * 2048 * 4);
  float* outb     = (float*)alloc((size_t)KBEAM * HDIM * 4);
  float* logits   = (float*)alloc((size_t)KBEAM * VOCAB * 4);
  float* rt_val   = (float*)alloc((size_t)KBEAM * 10 * 4);
  int*   rt_idx   = (int*)  alloc((size_t)KBEAM * 10 * 4);
  int*   tokA     = (int*)  alloc((size_t)KBEAM * TOKW * 4);
  int*   tokB     = (int*)  alloc((size_t)KBEAM * TOKW * 4);
  float* scores   = (float*)alloc((size_t)KBEAM * 4);
  int*   finished = (int*)  alloc((size_t)KBEAM * 4);
  unsigned* bar   = (unsigned*)alloc((size_t)18 * 64 * 4);
  (void)ws_size; (void)in_sizes; (void)n_in; (void)out_size;

  init_kernel<<<1, 256, 0, stream>>>(h0, c0, tokA, scores, finished, h_cur, c_cur, prev_cur, bar);
  keys_kernel<<<256, 256, 0, stream>>>(enc, Wap, keys);

  step_kernel<<<NBLK, 256, 0, stream>>>(
      enc, emb, W_ih, b_ih, W_hh, b_hh, Wc, Wv, keys, src_len,
      gates, h_cur, c_cur, prev_cur, h_new, c_new, ctx, outb, logits,
      rt_val, rt_idx, tokA, tokB, scores, finished, bar, (float*)d_out);
}